// Round 1
// baseline (300.357 us; speedup 1.0000x reference)
//
#include <hip/hip_runtime.h>

#define DIM 128

// ---------------------------------------------------------------------------
// Kernel 1: per-graph start offsets from sorted segment_ids.
// offs[g] = first row with seg >= g ; offs[G] = N. Handles empty graphs.
// ---------------------------------------------------------------------------
__global__ void k_offsets(const int* __restrict__ seg, int* __restrict__ offs,
                          int n, int ngraphs) {
    int i = blockIdx.x * blockDim.x + threadIdx.x;
    if (i >= n) return;
    int a = seg[i];
    if (i == 0) {
        for (int g = 0; g <= a; ++g) offs[g] = 0;
    } else {
        int p = seg[i - 1];
        for (int g = p + 1; g <= a; ++g) offs[g] = i;
    }
    if (i == n - 1) {
        for (int g = a + 1; g <= ngraphs; ++g) offs[g] = n;
    }
}

// ---------------------------------------------------------------------------
// Kernel 2: segment sums. 4 blocks per graph, each sums a quarter of the
// graph's rows. 256 threads: tx (0..31) = float4 column, ty (0..7) = row
// group. Deterministic per-quarter partials (no float atomics).
// partial layout: [4][G][DIM]
// ---------------------------------------------------------------------------
__global__ __launch_bounds__(256) void k_segsum(const float* __restrict__ h,
                                                const int* __restrict__ offs,
                                                float* __restrict__ partial,
                                                int ngraphs) {
    const int b = blockIdx.x;
    const int g = b >> 2;
    const int q = b & 3;
    const int s = offs[g];
    const int e = offs[g + 1];
    const int n = e - s;
    const int per = (n + 3) >> 2;
    const int rs = s + q * per;
    const int re = min(rs + per, e);

    const int tx = threadIdx.x & 31;   // float4 column
    const int ty = threadIdx.x >> 5;   // row slot (8 rows in flight)

    float4 acc = make_float4(0.f, 0.f, 0.f, 0.f);
    for (int r = rs + ty; r < re; r += 8) {
        const float4 v =
            *reinterpret_cast<const float4*>(h + (size_t)r * DIM + tx * 4);
        acc.x += v.x; acc.y += v.y; acc.z += v.z; acc.w += v.w;
    }

    __shared__ float4 red[8][32];
    red[ty][tx] = acc;
    __syncthreads();
    if (ty == 0) {
        float4 t = red[0][tx];
        #pragma unroll
        for (int i = 1; i < 8; ++i) {
            float4 u = red[i][tx];
            t.x += u.x; t.y += u.y; t.z += u.z; t.w += u.w;
        }
        *reinterpret_cast<float4*>(
            partial + ((size_t)q * ngraphs + g) * DIM + tx * 4) = t;
    }
}

// ---------------------------------------------------------------------------
// Kernel 3: virtual-node update. One block per graph, 128 threads.
// pool = sum/count ; x = vn_h + pool ; vn_new = vn_h + relu(x @ W + b)
// Thread d walks column d of W: at step k, threads 0..127 read W[k*128+d]
// (contiguous 512B, coalesced; W is L2-resident after first touch).
// ---------------------------------------------------------------------------
__global__ __launch_bounds__(128) void k_vn(const float* __restrict__ vn_h,
                                            const float* __restrict__ W,
                                            const float* __restrict__ bias,
                                            const float* __restrict__ partial,
                                            const int* __restrict__ offs,
                                            float* __restrict__ vn_out,
                                            int ngraphs) {
    const int g = blockIdx.x;
    const int d = threadIdx.x;
    const int cnt = offs[g + 1] - offs[g];
    const float inv = 1.0f / (float)max(cnt, 1);

    float sum = partial[((size_t)0 * ngraphs + g) * DIM + d]
              + partial[((size_t)1 * ngraphs + g) * DIM + d]
              + partial[((size_t)2 * ngraphs + g) * DIM + d]
              + partial[((size_t)3 * ngraphs + g) * DIM + d];
    const float vh = vn_h[(size_t)g * DIM + d];
    const float x = vh + sum * inv;

    __shared__ float xs[DIM];
    xs[d] = x;
    __syncthreads();

    float dot = bias[d];
    #pragma unroll
    for (int k = 0; k < DIM; ++k)
        dot = fmaf(xs[k], W[k * DIM + d], dot);

    vn_out[(size_t)g * DIM + d] = vh + fmaxf(dot, 0.0f);
}

// ---------------------------------------------------------------------------
// Kernel 4: h_new = h + vn_new[seg]. Grid-stride float4 stream.
// 32 lanes cover one 128-dim row; seg load is uniform within the 32-lane
// group (L1 broadcast); vn_new is a 512 KB L2-resident table.
// ---------------------------------------------------------------------------
__global__ __launch_bounds__(256) void k_scatter(const float* __restrict__ h,
                                                 const int* __restrict__ seg,
                                                 const float* __restrict__ vn_new,
                                                 float* __restrict__ h_out,
                                                 int n) {
    const int total = n * (DIM / 4);           // float4 elements
    const int stride = gridDim.x * blockDim.x;
    for (int i = blockIdx.x * blockDim.x + threadIdx.x; i < total; i += stride) {
        const int r = i >> 5;                  // row
        const int c = (i & 31) * 4;            // float col
        const int g = seg[r];
        const float4 hv =
            *reinterpret_cast<const float4*>(h + (size_t)r * DIM + c);
        const float4 vv =
            *reinterpret_cast<const float4*>(vn_new + (size_t)g * DIM + c);
        float4 o;
        o.x = hv.x + vv.x; o.y = hv.y + vv.y;
        o.z = hv.z + vv.z; o.w = hv.w + vv.w;
        *reinterpret_cast<float4*>(h_out + (size_t)r * DIM + c) = o;
    }
}

// ---------------------------------------------------------------------------
extern "C" void kernel_launch(void* const* d_in, const int* in_sizes, int n_in,
                              void* d_out, int out_size, void* d_ws, size_t ws_size,
                              hipStream_t stream) {
    const float* h    = (const float*)d_in[0];
    const float* vn_h = (const float*)d_in[1];
    const int*   seg  = (const int*)d_in[2];
    const float* W    = (const float*)d_in[3];
    const float* bias = (const float*)d_in[4];

    const int N = in_sizes[0] / DIM;   // 1,000,000
    const int G = in_sizes[1] / DIM;   // 1024

    float* out    = (float*)d_out;
    float* vn_out = out;                       // [G*DIM]
    float* h_out  = out + (size_t)G * DIM;     // [N*DIM]

    // Scratch: partial sums [4][G][DIM] f32 + offs [G+1] int.
    const size_t partial_floats = (size_t)4 * G * DIM;
    const size_t need = partial_floats * sizeof(float) + (size_t)(G + 1) * sizeof(int);

    float* partial;
    int*   offs;
    if (ws_size >= need) {
        partial = (float*)d_ws;
        offs    = (int*)((char*)d_ws + partial_floats * sizeof(float));
    } else {
        // Stash scratch inside the h_new region of d_out; it is fully
        // consumed by k_vn before k_scatter overwrites it.
        partial = h_out;
        offs    = (int*)(h_out + partial_floats);
    }

    hipLaunchKernelGGL(k_offsets, dim3((N + 255) / 256), dim3(256), 0, stream,
                       seg, offs, N, G);
    hipLaunchKernelGGL(k_segsum, dim3(G * 4), dim3(256), 0, stream,
                       h, offs, partial, G);
    hipLaunchKernelGGL(k_vn, dim3(G), dim3(DIM), 0, stream,
                       vn_h, W, bias, partial, offs, vn_out, G);

    const int total4 = N * (DIM / 4);
    int nb = (total4 + 255) / 256;
    if (nb > 2048) nb = 2048;
    hipLaunchKernelGGL(k_scatter, dim3(nb), dim3(256), 0, stream,
                       h, seg, vn_out, h_out, N);
}

// Round 3
// 274.749 us; speedup vs baseline: 1.0932x; 1.0932x over previous
//
#include <hip/hip_runtime.h>

#define DIM 128

typedef float fx4 __attribute__((ext_vector_type(4)));

// ---------------------------------------------------------------------------
// Kernel 1: per-graph start offsets from sorted segment_ids.
// offs[g] = first row with seg >= g ; offs[G] = N. Handles empty graphs.
// ---------------------------------------------------------------------------
__global__ void k_offsets(const int* __restrict__ seg, int* __restrict__ offs,
                          int n, int ngraphs) {
    int i = blockIdx.x * blockDim.x + threadIdx.x;
    if (i >= n) return;
    int a = seg[i];
    if (i == 0) {
        for (int g = 0; g <= a; ++g) offs[g] = 0;
    } else {
        int p = seg[i - 1];
        for (int g = p + 1; g <= a; ++g) offs[g] = i;
    }
    if (i == n - 1) {
        for (int g = a + 1; g <= ngraphs; ++g) offs[g] = n;
    }
}

// ---------------------------------------------------------------------------
// Kernel 2: segment sums. 4 blocks per graph, each sums a quarter of the
// graph's rows. 256 threads: tx (0..31) = float4 column, ty (0..7) = row
// group. Deterministic per-quarter partials (no float atomics).
// partial layout: [4][G][DIM]
// h is read FORWARD here; the tail of h stays L3-resident for k_scatter,
// which reads in reverse.
// ---------------------------------------------------------------------------
__global__ __launch_bounds__(256) void k_segsum(const float* __restrict__ h,
                                                const int* __restrict__ offs,
                                                float* __restrict__ partial,
                                                int ngraphs) {
    const int b = blockIdx.x;
    const int g = b >> 2;
    const int q = b & 3;
    const int s = offs[g];
    const int e = offs[g + 1];
    const int n = e - s;
    const int per = (n + 3) >> 2;
    const int rs = s + q * per;
    const int re = min(rs + per, e);

    const int tx = threadIdx.x & 31;   // float4 column
    const int ty = threadIdx.x >> 5;   // row slot (8 rows in flight)

    float4 acc = make_float4(0.f, 0.f, 0.f, 0.f);
    for (int r = rs + ty; r < re; r += 8) {
        const float4 v =
            *reinterpret_cast<const float4*>(h + (size_t)r * DIM + tx * 4);
        acc.x += v.x; acc.y += v.y; acc.z += v.z; acc.w += v.w;
    }

    __shared__ float4 red[8][32];
    red[ty][tx] = acc;
    __syncthreads();
    if (ty == 0) {
        float4 t = red[0][tx];
        #pragma unroll
        for (int i = 1; i < 8; ++i) {
            float4 u = red[i][tx];
            t.x += u.x; t.y += u.y; t.z += u.z; t.w += u.w;
        }
        *reinterpret_cast<float4*>(
            partial + ((size_t)q * ngraphs + g) * DIM + tx * 4) = t;
    }
}

// ---------------------------------------------------------------------------
// Kernel 3: virtual-node update. One block per graph, 128 threads.
// pool = sum/count ; x = vn_h + pool ; vn_new = vn_h + relu(x @ W + b)
// ---------------------------------------------------------------------------
__global__ __launch_bounds__(128) void k_vn(const float* __restrict__ vn_h,
                                            const float* __restrict__ W,
                                            const float* __restrict__ bias,
                                            const float* __restrict__ partial,
                                            const int* __restrict__ offs,
                                            float* __restrict__ vn_out,
                                            int ngraphs) {
    const int g = blockIdx.x;
    const int d = threadIdx.x;
    const int cnt = offs[g + 1] - offs[g];
    const float inv = 1.0f / (float)max(cnt, 1);

    float sum = partial[((size_t)0 * ngraphs + g) * DIM + d]
              + partial[((size_t)1 * ngraphs + g) * DIM + d]
              + partial[((size_t)2 * ngraphs + g) * DIM + d]
              + partial[((size_t)3 * ngraphs + g) * DIM + d];
    const float vh = vn_h[(size_t)g * DIM + d];
    const float x = vh + sum * inv;

    __shared__ float xs[DIM];
    xs[d] = x;
    __syncthreads();

    float dot = bias[d];
    #pragma unroll
    for (int k = 0; k < DIM; ++k)
        dot = fmaf(xs[k], W[k * DIM + d], dot);

    vn_out[(size_t)g * DIM + d] = vh + fmaxf(dot, 0.0f);
}

// ---------------------------------------------------------------------------
// Kernel 4: h_new = h + vn_new[seg]. Grid-stride float4 stream in REVERSE
// row order: k_segsum just streamed h forward, so the tail ~256 MB of h is
// Infinity-Cache-resident — consume it first. h_out uses nontemporal stores
// (native ext_vector_type — HIP float4 is rejected by the builtin) so the
// write stream doesn't evict the cached h tail (h_out is never re-read).
// ---------------------------------------------------------------------------
__global__ __launch_bounds__(256) void k_scatter(const float* __restrict__ h,
                                                 const int* __restrict__ seg,
                                                 const float* __restrict__ vn_new,
                                                 float* __restrict__ h_out,
                                                 int n) {
    const int total = n * (DIM / 4);           // float4 elements (32e6 < 2^31)
    const int stride = gridDim.x * blockDim.x;
    for (int i = blockIdx.x * blockDim.x + threadIdx.x; i < total; i += stride) {
        const int j = total - 1 - i;           // reversed walk, still coalesced
        const int r = j >> 5;                  // row
        const int c = (j & 31) * 4;            // float col
        const int g = seg[r];
        const fx4 hv =
            *reinterpret_cast<const fx4*>(h + (size_t)r * DIM + c);
        const fx4 vv =
            *reinterpret_cast<const fx4*>(vn_new + (size_t)g * DIM + c);
        const fx4 o = hv + vv;
        __builtin_nontemporal_store(
            o, reinterpret_cast<fx4*>(h_out + (size_t)r * DIM + c));
    }
}

// ---------------------------------------------------------------------------
extern "C" void kernel_launch(void* const* d_in, const int* in_sizes, int n_in,
                              void* d_out, int out_size, void* d_ws, size_t ws_size,
                              hipStream_t stream) {
    const float* h    = (const float*)d_in[0];
    const float* vn_h = (const float*)d_in[1];
    const int*   seg  = (const int*)d_in[2];
    const float* W    = (const float*)d_in[3];
    const float* bias = (const float*)d_in[4];

    const int N = in_sizes[0] / DIM;   // 1,000,000
    const int G = in_sizes[1] / DIM;   // 1024

    float* out    = (float*)d_out;
    float* vn_out = out;                       // [G*DIM]
    float* h_out  = out + (size_t)G * DIM;     // [N*DIM]

    // Scratch: partial sums [4][G][DIM] f32 + offs [G+1] int.
    const size_t partial_floats = (size_t)4 * G * DIM;
    const size_t need = partial_floats * sizeof(float) + (size_t)(G + 1) * sizeof(int);

    float* partial;
    int*   offs;
    if (ws_size >= need) {
        partial = (float*)d_ws;
        offs    = (int*)((char*)d_ws + partial_floats * sizeof(float));
    } else {
        // Stash scratch inside the h_new region of d_out; it is fully
        // consumed by k_vn before k_scatter overwrites it.
        partial = h_out;
        offs    = (int*)(h_out + partial_floats);
    }

    hipLaunchKernelGGL(k_offsets, dim3((N + 255) / 256), dim3(256), 0, stream,
                       seg, offs, N, G);
    hipLaunchKernelGGL(k_segsum, dim3(G * 4), dim3(256), 0, stream,
                       h, offs, partial, G);
    hipLaunchKernelGGL(k_vn, dim3(G), dim3(DIM), 0, stream,
                       vn_h, W, bias, partial, offs, vn_out, G);

    const int total4 = N * (DIM / 4);
    int nb = (total4 + 255) / 256;
    if (nb > 2048) nb = 2048;
    hipLaunchKernelGGL(k_scatter, dim3(nb), dim3(256), 0, stream,
                       h, seg, vn_out, h_out, N);
}

// Round 4
// 261.713 us; speedup vs baseline: 1.1477x; 1.0498x over previous
//
#include <hip/hip_runtime.h>

#define DIM 128

typedef float fx4 __attribute__((ext_vector_type(4)));

// ---------------------------------------------------------------------------
// Kernel 1: per-graph start offsets from sorted segment_ids.
// offs[g] = first row with seg >= g ; offs[G] = N. Handles empty graphs.
// shfl_up shares seg[i] with lane+1 so we read seg ~once, not twice.
// ---------------------------------------------------------------------------
__global__ void k_offsets(const int* __restrict__ seg, int* __restrict__ offs,
                          int n, int ngraphs) {
    const int i = blockIdx.x * blockDim.x + threadIdx.x;
    const int a = (i < n) ? seg[i] : 0;
    int p = __shfl_up(a, 1);          // all lanes participate before any exit
    if (i >= n) return;
    if (i == 0) {
        for (int g = 0; g <= a; ++g) offs[g] = 0;
    } else {
        if ((threadIdx.x & 63) == 0) p = seg[i - 1];   // wave boundary
        for (int g = p + 1; g <= a; ++g) offs[g] = i;
    }
    if (i == n - 1) {
        for (int g = a + 1; g <= ngraphs; ++g) offs[g] = n;
    }
}

// ---------------------------------------------------------------------------
// Kernel 2: segment sums. 8 blocks per graph (q = eighth), 256 threads:
// tx (0..31) = float4 column, ty (0..7) = row slot. 2-deep unrolled dual
// accumulators for MLP. Deterministic per-eighth partials (no atomics).
// partial layout: [8][G][DIM].
// L3 discipline: blocks entirely below cut_row use nontemporal loads so the
// head of h never allocates in Infinity Cache; only the ~218 MB tail stays
// resident for k_scatter's reverse walk.
// ---------------------------------------------------------------------------
__global__ __launch_bounds__(256) void k_segsum(const float* __restrict__ h,
                                                const int* __restrict__ offs,
                                                float* __restrict__ partial,
                                                int ngraphs, int cut_row) {
    const int b = blockIdx.x;
    const int g = b >> 3;
    const int q = b & 7;
    const int s = offs[g];
    const int e = offs[g + 1];
    const int n = e - s;
    const int per = (n + 7) >> 3;
    const int rs = s + q * per;
    const int re = min(rs + per, e);

    const int tx = threadIdx.x & 31;   // float4 column
    const int ty = threadIdx.x >> 5;   // row slot (8 rows in flight)

    fx4 acc  = {0.f, 0.f, 0.f, 0.f};
    fx4 acc2 = {0.f, 0.f, 0.f, 0.f};
    int r = rs + ty;
    if (re <= cut_row) {               // head region: bypass cache allocation
        for (; r + 8 < re; r += 16) {
            acc  += __builtin_nontemporal_load(
                        reinterpret_cast<const fx4*>(h + (size_t)r * DIM + tx * 4));
            acc2 += __builtin_nontemporal_load(
                        reinterpret_cast<const fx4*>(h + (size_t)(r + 8) * DIM + tx * 4));
        }
        if (r < re)
            acc += __builtin_nontemporal_load(
                       reinterpret_cast<const fx4*>(h + (size_t)r * DIM + tx * 4));
    } else {                           // tail region: allocate (stays in L3)
        for (; r + 8 < re; r += 16) {
            acc  += *reinterpret_cast<const fx4*>(h + (size_t)r * DIM + tx * 4);
            acc2 += *reinterpret_cast<const fx4*>(h + (size_t)(r + 8) * DIM + tx * 4);
        }
        if (r < re)
            acc += *reinterpret_cast<const fx4*>(h + (size_t)r * DIM + tx * 4);
    }
    acc += acc2;

    __shared__ fx4 red[8][32];
    red[ty][tx] = acc;
    __syncthreads();
    if (ty == 0) {
        fx4 t = red[0][tx];
        #pragma unroll
        for (int i = 1; i < 8; ++i) t += red[i][tx];
        *reinterpret_cast<fx4*>(
            partial + ((size_t)q * ngraphs + g) * DIM + tx * 4) = t;
    }
}

// ---------------------------------------------------------------------------
// Kernel 3: virtual-node update. One block per graph, 128 threads.
// pool = sum/count ; x = vn_h + pool ; vn_new = vn_h + relu(x @ W + b)
// ---------------------------------------------------------------------------
__global__ __launch_bounds__(128) void k_vn(const float* __restrict__ vn_h,
                                            const float* __restrict__ W,
                                            const float* __restrict__ bias,
                                            const float* __restrict__ partial,
                                            const int* __restrict__ offs,
                                            float* __restrict__ vn_out,
                                            int ngraphs) {
    const int g = blockIdx.x;
    const int d = threadIdx.x;
    const int cnt = offs[g + 1] - offs[g];
    const float inv = 1.0f / (float)max(cnt, 1);

    float sum = 0.f;
    #pragma unroll
    for (int p = 0; p < 8; ++p)
        sum += partial[((size_t)p * ngraphs + g) * DIM + d];
    const float vh = vn_h[(size_t)g * DIM + d];
    const float x = vh + sum * inv;

    __shared__ float xs[DIM];
    xs[d] = x;
    __syncthreads();

    float dot = bias[d];
    #pragma unroll
    for (int k = 0; k < DIM; ++k)
        dot = fmaf(xs[k], W[k * DIM + d], dot);

    vn_out[(size_t)g * DIM + d] = vh + fmaxf(dot, 0.0f);
}

// ---------------------------------------------------------------------------
// Kernel 4: h_new = h + vn_new[seg]. Grid-stride float4 stream in REVERSE
// row order: consume the L3-resident tail of h first. h reads are
// nontemporal (this is the last-ever read of h; hits still hit, no
// re-allocation churn). vn_new (512 KB) stays cache-allocated (hot reuse).
// h_out uses nontemporal stores (pure streaming, never re-read).
// ---------------------------------------------------------------------------
__global__ __launch_bounds__(256) void k_scatter(const float* __restrict__ h,
                                                 const int* __restrict__ seg,
                                                 const float* __restrict__ vn_new,
                                                 float* __restrict__ h_out,
                                                 int n) {
    const int total = n * (DIM / 4);           // float4 elements (32e6 < 2^31)
    const int stride = gridDim.x * blockDim.x;
    for (int i = blockIdx.x * blockDim.x + threadIdx.x; i < total; i += stride) {
        const int j = total - 1 - i;           // reversed walk, still coalesced
        const int r = j >> 5;                  // row
        const int c = (j & 31) * 4;            // float col
        const int g = seg[r];
        const fx4 hv = __builtin_nontemporal_load(
            reinterpret_cast<const fx4*>(h + (size_t)r * DIM + c));
        const fx4 vv =
            *reinterpret_cast<const fx4*>(vn_new + (size_t)g * DIM + c);
        const fx4 o = hv + vv;
        __builtin_nontemporal_store(
            o, reinterpret_cast<fx4*>(h_out + (size_t)r * DIM + c));
    }
}

// ---------------------------------------------------------------------------
extern "C" void kernel_launch(void* const* d_in, const int* in_sizes, int n_in,
                              void* d_out, int out_size, void* d_ws, size_t ws_size,
                              hipStream_t stream) {
    const float* h    = (const float*)d_in[0];
    const float* vn_h = (const float*)d_in[1];
    const int*   seg  = (const int*)d_in[2];
    const float* W    = (const float*)d_in[3];
    const float* bias = (const float*)d_in[4];

    const int N = in_sizes[0] / DIM;   // 1,000,000
    const int G = in_sizes[1] / DIM;   // 1024

    float* out    = (float*)d_out;
    float* vn_out = out;                       // [G*DIM]
    float* h_out  = out + (size_t)G * DIM;     // [N*DIM]

    // Scratch: partial sums [8][G][DIM] f32 + offs [G+1] int.
    const size_t partial_floats = (size_t)8 * G * DIM;
    const size_t need = partial_floats * sizeof(float) + (size_t)(G + 1) * sizeof(int);

    float* partial;
    int*   offs;
    if (ws_size >= need) {
        partial = (float*)d_ws;
        offs    = (int*)((char*)d_ws + partial_floats * sizeof(float));
    } else {
        // Stash scratch inside the h_new region of d_out; it is fully
        // consumed by k_vn before k_scatter overwrites it.
        partial = h_out;
        offs    = (int*)(h_out + partial_floats);
    }

    // Rows >= cut_row (~218 MB tail) are allowed to allocate in L3;
    // everything below streams via nt-loads.
    int cut_row = N - 425000;
    if (cut_row < 0) cut_row = 0;

    hipLaunchKernelGGL(k_offsets, dim3((N + 255) / 256), dim3(256), 0, stream,
                       seg, offs, N, G);
    hipLaunchKernelGGL(k_segsum, dim3(G * 8), dim3(256), 0, stream,
                       h, offs, partial, G, cut_row);
    hipLaunchKernelGGL(k_vn, dim3(G), dim3(DIM), 0, stream,
                       vn_h, W, bias, partial, offs, vn_out, G);

    const int total4 = N * (DIM / 4);
    int nb = (total4 + 255) / 256;
    if (nb > 2048) nb = 2048;
    hipLaunchKernelGGL(k_scatter, dim3(nb), dim3(256), 0, stream,
                       h, seg, vn_out, h_out, N);
}